// Round 11
// baseline (35.626 us; speedup 1.0000x reference)
//
#include <hip/hip_runtime.h>
#include <math.h>

// dims: B=4096, D=64, K=64, DM=512
// Workspace layout (float offsets)
#define WS_INV    0
#define WS_INVSV  1
#define WS_BOVW   2
#define WS_BVWO   3
#define WS_N2V    4
#define WS_COLSUM 64          // 64
#define WS_A      128         // 64*64
#define WS_WO0    4224        // 512
#define WS_QZB    4736        // 512
#define WS_CK0    5248        // 64  (unscaled)
#define WS_CVW    5312        // 64  (unscaled)
#define WS_T1     16384       // T1t[f][k] 512*64
#define WS_V1     49152       // V1t[e][k] 512*64
#define WS_P1     81920       // P1[f][d]  512*64
#define WS_GT     147456      // 4096 final Gt[d][k] (unscaled)

#define PRE_LDSB  (36928 * 4)   // 147712 B
#define MID_LDSB  (36864 * 4)   // 147456 B (T1 full 32768 + P1 cols 4096)

__device__ __forceinline__ float wave_sum(float x) {
#pragma unroll
    for (int o = 32; o; o >>= 1) x += __shfl_xor(x, o);
    return x;
}

__device__ __forceinline__ float block_sum512(float v, float* red) {
    float s = wave_sum(v);
    const int wid = threadIdx.x >> 6;
    __syncthreads();
    if ((threadIdx.x & 63) == 0) red[wid] = s;
    __syncthreads();
    float t2 = 0.0f;
#pragma unroll
    for (int i = 0; i < 8; ++i) t2 += red[i];
    return t2;
}

// ===========================================================================
// K1: 217 blocks x 512 threads. All level-0 (inputs only). Proven structure.
// ===========================================================================
__global__ __launch_bounds__(512) void k_pre(
    const float* __restrict__ zW, const float* __restrict__ zb,
    const float* __restrict__ Wq, const float* __restrict__ bq,
    const float* __restrict__ Wk, const float* __restrict__ Wv,
    const float* __restrict__ Wo, const float* __restrict__ ce,
    const float* __restrict__ vW, const float* __restrict__ bo,
    float* __restrict__ ws)
{
    extern __shared__ float sm[];
    const int blk = blockIdx.x, t = threadIdx.x;
    const int lane = t & 63, w = t >> 6;

    if (blk < 128) {
        // ---------------- T1t / V1t ----------------
        const int f0 = blk * 4;
        float* ces = sm;            // 64*513
        float* wkv = sm + 32832;    // 8*512
        {
            const float4* ce4 = (const float4*)ce;
#pragma unroll 4
            for (int i = 0; i < 16; ++i) {
                const int idx4 = i * 512 + t;          // k*128 + c4
                const int k = idx4 >> 7, c4 = idx4 & 127;
                const float4 v = ce4[idx4];
                float* dst = &ces[k * 513 + c4 * 4];
                dst[0] = v.x; dst[1] = v.y; dst[2] = v.z; dst[3] = v.w;
            }
        }
        {
            const float4* Wk4 = (const float4*)Wk;
            const float4* Wv4 = (const float4*)Wv;
            float4* wkv4 = (float4*)wkv;
#pragma unroll
            for (int i = 0; i < 2; ++i) {
                const int idx = i * 512 + t;
                const int a = idx >> 7, c4 = idx & 127;
                wkv4[idx] = (a < 4) ? Wk4[(f0 + a) * 128 + c4]
                                    : Wv4[(f0 + a - 4) * 128 + c4];
            }
        }
        __syncthreads();
        float acc[8];
#pragma unroll
        for (int a = 0; a < 8; ++a) acc[a] = 0.0f;
        const int c0 = w * 64;
#pragma unroll 2
        for (int q4 = 0; q4 < 16; ++q4) {
            const int c = c0 + q4 * 4;
            const float cv0 = ces[lane * 513 + c + 0];
            const float cv1 = ces[lane * 513 + c + 1];
            const float cv2 = ces[lane * 513 + c + 2];
            const float cv3 = ces[lane * 513 + c + 3];
#pragma unroll
            for (int a = 0; a < 8; ++a) {
                const float4 wv4 = *(const float4*)&wkv[a * 512 + c];
                acc[a] = fmaf(wv4.x, cv0, acc[a]);
                acc[a] = fmaf(wv4.y, cv1, acc[a]);
                acc[a] = fmaf(wv4.z, cv2, acc[a]);
                acc[a] = fmaf(wv4.w, cv3, acc[a]);
            }
        }
        __syncthreads();
        float* part = sm;                              // reuse, 64*65
#pragma unroll
        for (int a = 0; a < 8; ++a) part[(a * 8 + w) * 65 + lane] = acc[a];
        __syncthreads();
        {
            float s = 0.0f;
#pragma unroll
            for (int ww = 0; ww < 8; ++ww) s += part[(w * 8 + ww) * 65 + lane];
            if (w < 4) ws[WS_T1 + (f0 + w) * 64 + lane] = s;
            else       ws[WS_V1 + (f0 + w - 4) * 64 + lane] = s;
        }

    } else if (blk < 192) {
        // ---------------- P1 ----------------
        const int f0 = (blk - 128) * 8;
        float* zl = sm;             // 512*64
        float* wq = sm + 32768;     // 8*512
        {
            const float4* zW4 = (const float4*)zW;
            float4* zl4 = (float4*)zl;
#pragma unroll 4
            for (int i = 0; i < 16; ++i) zl4[i * 512 + t] = zW4[i * 512 + t];
            const float4* Wq4 = (const float4*)Wq;
            float4* wq4 = (float4*)wq;
#pragma unroll
            for (int i = 0; i < 2; ++i)
                wq4[i * 512 + t] = Wq4[f0 * 128 + i * 512 + t];
        }
        __syncthreads();
        float acc[8];
#pragma unroll
        for (int a = 0; a < 8; ++a) acc[a] = 0.0f;
        const int e0 = w * 64;
#pragma unroll 2
        for (int q4 = 0; q4 < 16; ++q4) {
            const int e = e0 + q4 * 4;
            const float z0 = zl[(e + 0) * 64 + lane];
            const float z1 = zl[(e + 1) * 64 + lane];
            const float z2 = zl[(e + 2) * 64 + lane];
            const float z3 = zl[(e + 3) * 64 + lane];
#pragma unroll
            for (int fi = 0; fi < 8; ++fi) {
                const float4 q4v = *(const float4*)&wq[fi * 512 + e];
                acc[fi] = fmaf(q4v.x, z0, acc[fi]);
                acc[fi] = fmaf(q4v.y, z1, acc[fi]);
                acc[fi] = fmaf(q4v.z, z2, acc[fi]);
                acc[fi] = fmaf(q4v.w, z3, acc[fi]);
            }
        }
        __syncthreads();
        float* part = sm;
#pragma unroll
        for (int a = 0; a < 8; ++a) part[(a * 8 + w) * 65 + lane] = acc[a];
        __syncthreads();
        {
            float s = 0.0f;
#pragma unroll
            for (int ww = 0; ww < 8; ++ww) s += part[(w * 8 + ww) * 65 + lane];
            ws[WS_P1 + (f0 + w) * 64 + lane] = s;
        }

    } else if (blk < 200) {
        // ---------------- A = zW^T zW (+ colsum on first) ----------------
        const int r0 = (blk - 192) * 8;
        float* zl = sm;
        {
            const float4* zW4 = (const float4*)zW;
            float4* zl4 = (float4*)zl;
#pragma unroll 4
            for (int i = 0; i < 16; ++i) zl4[i * 512 + t] = zW4[i * 512 + t];
        }
        __syncthreads();
        float acc[8];
#pragma unroll
        for (int a = 0; a < 8; ++a) acc[a] = 0.0f;
        float cs = 0.0f;
        const int e0 = w * 64;
#pragma unroll 2
        for (int q4 = 0; q4 < 16; ++q4) {
            const int e = e0 + q4 * 4;
#pragma unroll
            for (int j = 0; j < 4; ++j) {
                const float zv = zl[(e + j) * 64 + lane];
                cs += zv;
                const float4 b0 = *(const float4*)&zl[(e + j) * 64 + r0];
                const float4 b1 = *(const float4*)&zl[(e + j) * 64 + r0 + 4];
                acc[0] = fmaf(b0.x, zv, acc[0]);
                acc[1] = fmaf(b0.y, zv, acc[1]);
                acc[2] = fmaf(b0.z, zv, acc[2]);
                acc[3] = fmaf(b0.w, zv, acc[3]);
                acc[4] = fmaf(b1.x, zv, acc[4]);
                acc[5] = fmaf(b1.y, zv, acc[5]);
                acc[6] = fmaf(b1.z, zv, acc[6]);
                acc[7] = fmaf(b1.w, zv, acc[7]);
            }
        }
        __syncthreads();
        float* part = sm;            // 64*65
        float* part2 = sm + 4160;    // 8*65
#pragma unroll
        for (int a = 0; a < 8; ++a) part[(a * 8 + w) * 65 + lane] = acc[a];
        if (blk == 192) part2[w * 65 + lane] = cs;
        __syncthreads();
        {
            float s = 0.0f;
#pragma unroll
            for (int ww = 0; ww < 8; ++ww) s += part[(w * 8 + ww) * 65 + lane];
            ws[WS_A + (r0 + w) * 64 + lane] = s;
        }
        if (blk == 192 && t < 64) {
            float s = 0.0f;
#pragma unroll
            for (int ww = 0; ww < 8; ++ww) s += part2[ww * 65 + t];
            ws[WS_COLSUM + t] = s;
        }

    } else if (blk < 208) {
        // ---------------- qzb ----------------
        const int f0 = (blk - 200) * 64;
        float zbr[8];
#pragma unroll
        for (int i = 0; i < 8; ++i) zbr[i] = zb[i * 64 + lane];
#pragma unroll
        for (int ff = 0; ff < 8; ++ff) {
            const int f = f0 + w * 8 + ff;
            float s = 0.0f;
#pragma unroll
            for (int i = 0; i < 8; ++i)
                s = fmaf(Wq[f * 512 + i * 64 + lane], zbr[i], s);
            s = wave_sum(s);
            if (lane == 0) ws[WS_QZB + f] = s + bq[f];
        }

    } else if (blk < 216) {
        // ---------------- wo0 = Wo^T vW ----------------
        const int e0 = (blk - 208) * 64;
        float s = 0.0f;
#pragma unroll 4
        for (int gi = 0; gi < 64; ++gi) {
            const int g = w * 64 + gi;
            s = fmaf(Wo[g * 512 + e0 + lane], vW[g], s);
        }
        float* part = sm;
        part[w * 65 + lane] = s;
        __syncthreads();
        if (t < 64) {
            float o = 0.0f;
#pragma unroll
            for (int ww = 0; ww < 8; ++ww) o += part[ww * 65 + t];
            ws[WS_WO0 + e0 + t] = o;
        }

    } else {
        // ---------------- misc: n2v, bo.vW ----------------
        float* red = sm;
        const float vwt = vW[t];
        const float n2v = block_sum512(vwt * vwt, red);
        if (t == 0) ws[WS_N2V] = n2v;
        const float bv_ = block_sum512(bo[t] * vwt, red);
        if (t == 0) ws[WS_BOVW] = bv_;
    }
}

// ===========================================================================
// K2: 11 blocks x 512 threads (level-1). No atomics, no fences.
//  b0   : closed-form sigma (512-thread matvecs) + bv.wo0 + sigma_v
//  b1,b2: cvw0 = V1 @ wo0 ; ck0 = T1 @ qzb  (unscaled)
//  b3-10: GT-direct: block owns d-octet d0=(blk-3)*8; full T1 + 8 P1 columns
//         staged in LDS; wave w computes f-slice [64w,64w+64) partial acc[8];
//         intra-block LDS reduce in ascending wave order (bitwise == r10).
// ===========================================================================
__global__ __launch_bounds__(512) void k_mid(
    const float* __restrict__ bv, float* __restrict__ ws)
{
    extern __shared__ float sm[];
    const int blk = blockIdx.x, t = threadIdx.x;
    const int lane = t & 63, w = t >> 6;

    if (blk == 0) {
        float* As = sm;           // 64*65
        float* wL = sm + 4160;    // 64
        float* mvL = sm + 4224;   // 64
#pragma unroll
        for (int i = 0; i < 8; ++i) {
            const int idx = i * 512 + t;
            As[(idx >> 6) * 65 + (idx & 63)] = ws[WS_A + idx];
        }
        if (t < 64) wL[t] = ws[WS_COLSUM + t];
        __syncthreads();
        const int row = t >> 3, sub = t & 7;
#pragma unroll
        for (int it = 0; it < 4; ++it) {
            float p = 0.0f;
#pragma unroll
            for (int j = 0; j < 8; ++j)
                p = fmaf(As[row * 65 + sub * 8 + j], wL[sub * 8 + j], p);
            p += __shfl_xor(p, 1);
            p += __shfl_xor(p, 2);
            p += __shfl_xor(p, 4);
            __syncthreads();
            if (sub == 0) wL[row] = p;
            __syncthreads();
        }
        {
            float p = 0.0f;
#pragma unroll
            for (int j = 0; j < 8; ++j)
                p = fmaf(As[row * 65 + sub * 8 + j], wL[sub * 8 + j], p);
            p += __shfl_xor(p, 1);
            p += __shfl_xor(p, 2);
            p += __shfl_xor(p, 4);
            if (sub == 0) mvL[row] = p;
            __syncthreads();
        }
        if (w == 0) {
            const float w4 = wL[lane], mv = mvL[lane];
            const float s8 = wave_sum(w4 * w4);
            const float s9 = wave_sum(mv * w4);
            const float den = sqrtf(s8) + 1e-12f;
            const float n5sq = s9 / (den * den);
            const float n5 = sqrtf(n5sq);
            const float sig = n5sq / (n5 + 1e-12f);
            if (lane == 0) ws[WS_INV] = 1.0f / sig;
        } else if (w == 1) {
            float s = 0.0f;
#pragma unroll
            for (int i = 0; i < 8; ++i)
                s = fmaf(bv[i * 64 + lane], ws[WS_WO0 + i * 64 + lane], s);
            s = wave_sum(s);
            if (lane == 0) ws[WS_BVWO] = s;
        } else if (w == 2 && lane == 0) {
            const float n2 = ws[WS_N2V];
            const float rn = sqrtf(n2);
            float u = 1.0f / (1.0f + 1e-12f), s = 0.0f;
            for (int it = 0; it < 5; ++it) {
                const float nv = fabsf(u) * rn;
                const float vs = u / (nv + 1e-12f);
                s = n2 * vs;
                u = s / (fabsf(s) + 1e-12f);
            }
            ws[WS_INVSV] = 1.0f / (u * s);
        }

    } else if (blk < 3) {
        const int mat = (blk == 1) ? WS_V1 : WS_T1;
        const int vec = (blk == 1) ? WS_WO0 : WS_QZB;
        const int dst = (blk == 1) ? WS_CVW : WS_CK0;
        float s = 0.0f;
#pragma unroll 8
        for (int i = 0; i < 64; ++i) {
            const int e = w * 64 + i;
            s = fmaf(ws[mat + e * 64 + lane], ws[vec + e], s);
        }
        float* part = sm;
        part[w * 65 + lane] = s;
        __syncthreads();
        if (t < 64) {
            float o = 0.0f;
#pragma unroll
            for (int ww = 0; ww < 8; ++ww) o += part[ww * 65 + t];
            ws[dst + t] = o;
        }

    } else {
        // ---- GT-direct for d-octet d0 ----
        const int d0 = (blk - 3) * 8;
        float* T1s = sm;            // 512*64 = 32768
        float* P1s = sm + 32768;    // 512*8  = 4096
        {
            const float4* a4 = (const float4*)&ws[WS_T1];
            float4* T14 = (float4*)T1s;
#pragma unroll 4
            for (int i = 0; i < 16; ++i)
                T14[i * 512 + t] = a4[i * 512 + t];
            // P1 columns d0..d0+7 for f = t
            const float4 p0 = *(const float4*)&ws[WS_P1 + t * 64 + d0];
            const float4 p1 = *(const float4*)&ws[WS_P1 + t * 64 + d0 + 4];
            P1s[t * 8 + 0] = p0.x; P1s[t * 8 + 1] = p0.y;
            P1s[t * 8 + 2] = p0.z; P1s[t * 8 + 3] = p0.w;
            P1s[t * 8 + 4] = p1.x; P1s[t * 8 + 5] = p1.y;
            P1s[t * 8 + 6] = p1.z; P1s[t * 8 + 7] = p1.w;
        }
        __syncthreads();
        float acc[8];
#pragma unroll
        for (int j = 0; j < 8; ++j) acc[j] = 0.0f;
#pragma unroll 2
        for (int fi = 0; fi < 64; ++fi) {
            const int f = w * 64 + fi;
            const float a = T1s[f * 64 + lane];
            const float4 p0 = *(const float4*)&P1s[f * 8];
            const float4 p1 = *(const float4*)&P1s[f * 8 + 4];
            acc[0] = fmaf(a, p0.x, acc[0]);
            acc[1] = fmaf(a, p0.y, acc[1]);
            acc[2] = fmaf(a, p0.z, acc[2]);
            acc[3] = fmaf(a, p0.w, acc[3]);
            acc[4] = fmaf(a, p1.x, acc[4]);
            acc[5] = fmaf(a, p1.y, acc[5]);
            acc[6] = fmaf(a, p1.z, acc[6]);
            acc[7] = fmaf(a, p1.w, acc[7]);
        }
        __syncthreads();
        float* part = sm;            // reuse (aliases T1s), 64*65
#pragma unroll
        for (int a = 0; a < 8; ++a) part[(a * 8 + w) * 65 + lane] = acc[a];
        __syncthreads();
        {
            float s = 0.0f;
#pragma unroll
            for (int ww = 0; ww < 8; ++ww) s += part[(w * 8 + ww) * 65 + lane];
            ws[WS_GT + (d0 + w) * 64 + lane] = s;   // unscaled
        }
    }
}

// ===========================================================================
// K3: main. 128 blocks x 512 threads; 32 rows/block, 4 rows/wave, lane = k.
// Inter-kernel dirty reads: 16 KB GT + 0.5 KB vectors + 4 scalars per block.
// Yt recomputed in-kernel from clean cc input (proven r8/r9/r10).
// ===========================================================================
__global__ __launch_bounds__(512) void k_main(
    const float* __restrict__ z, const float* __restrict__ rw,
    const float* __restrict__ geo, const float* __restrict__ vb,
    const float* __restrict__ cc, const float* __restrict__ ws,
    float* __restrict__ out)
{
    __shared__ float sGt[4096];
    __shared__ float sYt[4160];   // [64][65] padded
    __shared__ float sCvw[64], sCk0[64], sNy2[64], sSc[2];
    const int t = threadIdx.x;
    const int lane = t & 63, wid = t >> 6;
    const float inv_s = ws[WS_INV];
    const float inv_sv = ws[WS_INVSV];

    // ---- stage GT (scaled) ----
    {
        const float4* gt4 = (const float4*)(ws + WS_GT);
        float4* sGt4 = (float4*)sGt;
#pragma unroll
        for (int i = 0; i < 2; ++i) {
            float4 g = gt4[i * 512 + t];
            g.x *= inv_s; g.y *= inv_s; g.z *= inv_s; g.w *= inv_s;
            sGt4[i * 512 + t] = g;
        }
    }
    if (t < 64) {
        sCvw[t] = inv_sv * ws[WS_CVW + t];
        sCk0[t] = ws[WS_CK0 + t];
    }
    if (t == 0) {
        sSc[0] = inv_sv * (ws[WS_BVWO] + ws[WS_BOVW]) + vb[0];
        sSc[1] = geo[0];
    }
    // ---- recompute chart-center projection from cc (threads 0..255) ----
    if (t < 256) {
        const int k = t >> 2, q = t & 3;
        const float4* cc4 = (const float4*)cc;
        float4 v[4];
        float n2 = 0.0f;
#pragma unroll
        for (int j = 0; j < 4; ++j) {
            v[j] = cc4[k * 16 + q * 4 + j];
            n2 = fmaf(v[j].x, v[j].x, n2);
            n2 = fmaf(v[j].y, v[j].y, n2);
            n2 = fmaf(v[j].z, v[j].z, n2);
            n2 = fmaf(v[j].w, v[j].w, n2);
        }
        n2 += __shfl_xor(n2, 1);
        n2 += __shfl_xor(n2, 2);
        const float n = sqrtf(n2);
        const float scale = fminf(1.0f, (1.0f - 1e-5f) / fmaxf(n, 1e-12f));
        float s2 = 0.0f;
#pragma unroll
        for (int j = 0; j < 4; ++j) {
            const float y0 = v[j].x * scale, y1 = v[j].y * scale;
            const float y2 = v[j].z * scale, y3 = v[j].w * scale;
            const int dd = q * 16 + j * 4;
            sYt[(dd + 0) * 65 + k] = y0;
            sYt[(dd + 1) * 65 + k] = y1;
            sYt[(dd + 2) * 65 + k] = y2;
            sYt[(dd + 3) * 65 + k] = y3;
            s2 = fmaf(y0, y0, s2); s2 = fmaf(y1, y1, s2);
            s2 = fmaf(y2, y2, s2); s2 = fmaf(y3, y3, s2);
        }
        s2 += __shfl_xor(s2, 1);
        s2 += __shfl_xor(s2, 2);
        if (q == 0) sNy2[k] = s2;
    }
    __syncthreads();

    const float gs = sSc[1], cst = sSc[0];
    const float rs512 = 0.04419417382415922f;   // 1/sqrt(512)
#pragma unroll
    for (int rr = 0; rr < 4; ++rr) {
        const int b = blockIdx.x * 32 + wid * 4 + rr;
        const float zl = z[b * 64 + lane];
        const float rwk = rw[b * 64 + lane];
        float dot = 0.0f, diff2 = 0.0f, nz2 = 0.0f;
#pragma unroll 8
        for (int dd = 0; dd < 64; ++dd) {
            const float zd = __shfl(zl, dd);
            nz2 = fmaf(zd, zd, nz2);
            dot = fmaf(zd, sGt[dd * 64 + lane], dot);
            const float df = zd - sYt[dd * 65 + lane];
            diff2 = fmaf(df, df, diff2);
        }
        const float den = (1.0f - nz2) * (1.0f - sNy2[lane]);
        float arg = 1.0f + 2.0f * diff2 / fmaxf(den, 1e-12f);
        arg = fmaxf(arg, 1.0f + 1e-7f);
        const float dg = acoshf(arg);
        const float score = rwk * (dot + sCk0[lane]) * rs512 - gs * dg * dg;
        float mx = score;
#pragma unroll
        for (int o = 32; o; o >>= 1) mx = fmaxf(mx, __shfl_xor(mx, o));
        const float e = expf(score - mx);
        float s1 = e, s2 = e * rwk * sCvw[lane];
#pragma unroll
        for (int o = 32; o; o >>= 1) { s1 += __shfl_xor(s1, o); s2 += __shfl_xor(s2, o); }
        if (lane == 0) out[b] = s2 / s1 + cst;
    }
}

extern "C" void kernel_launch(void* const* d_in, const int* in_sizes, int n_in,
                              void* d_out, int out_size, void* d_ws, size_t ws_size,
                              hipStream_t stream)
{
    (void)in_sizes; (void)n_in; (void)out_size; (void)ws_size;
    const float* z   = (const float*)d_in[0];
    const float* rw  = (const float*)d_in[1];
    const float* cem = (const float*)d_in[2];
    const float* cc  = (const float*)d_in[3];
    const float* zW  = (const float*)d_in[4];
    const float* zb  = (const float*)d_in[5];
    const float* Wq  = (const float*)d_in[6];
    const float* bq  = (const float*)d_in[7];
    const float* Wk  = (const float*)d_in[8];
    // d_in[9] = bk: softmax-shift-invariant, provably unused
    const float* Wv  = (const float*)d_in[10];
    const float* bv  = (const float*)d_in[11];
    const float* Wo  = (const float*)d_in[12];
    const float* bo  = (const float*)d_in[13];
    const float* geo = (const float*)d_in[14];
    const float* vW  = (const float*)d_in[15];
    const float* vb  = (const float*)d_in[16];
    float* ws  = (float*)d_ws;
    float* out = (float*)d_out;

    hipLaunchKernelGGL(k_pre,  dim3(217), dim3(512), PRE_LDSB, stream,
                       zW, zb, Wq, bq, Wk, Wv, Wo, cem, vW, bo, ws);
    hipLaunchKernelGGL(k_mid,  dim3(11),  dim3(512), MID_LDSB, stream, bv, ws);
    hipLaunchKernelGGL(k_main, dim3(128), dim3(512), 0, stream,
                       z, rw, geo, vb, cc, ws, out);
}

// Round 12
// 29.970 us; speedup vs baseline: 1.1887x; 1.1887x over previous
//
#include <hip/hip_runtime.h>
#include <math.h>

// dims: B=4096, D=64, K=64, DM=512
// Workspace layout (float offsets)
#define WS_INV    0
#define WS_INVSV  1
#define WS_BOVW   2
#define WS_BVWO   3
#define WS_N2V    4
#define WS_COLSUM 64          // 64
#define WS_A      128         // 64*64
#define WS_WO0    4224        // 512
#define WS_QZB    4736        // 512
#define WS_CK0    5248        // 64  (unscaled)
#define WS_CVW    5312        // 64  (unscaled)
#define WS_T1     16384       // T1t[f][k] 512*64
#define WS_V1     49152       // V1t[e][k] 512*64
#define WS_P1     81920       // P1[f][d]  512*64
#define WS_GP     114688      // 8*4096 partial Gt[d][k] (64-f slices)
// FIN replicas: 8 copies, one per XCD (written by blocks with blk%8==r).
#define FIN0      147456
#define FINSZ     4352        // GT 4096 | CVW 4096.. | CK0 4160.. | CST 4224 | GS 4225
#define FIN_CVW   4096
#define FIN_CK0   4160
#define FIN_CST   4224
#define FIN_GS    4225

#define PRE_LDSB  (36928 * 4)   // 147712 B
#define MID_LDSB  (8192 * 4)    // 32768 B

__device__ __forceinline__ float wave_sum(float x) {
#pragma unroll
    for (int o = 32; o; o >>= 1) x += __shfl_xor(x, o);
    return x;
}

__device__ __forceinline__ float block_sum512(float v, float* red) {
    float s = wave_sum(v);
    const int wid = threadIdx.x >> 6;
    __syncthreads();
    if ((threadIdx.x & 63) == 0) red[wid] = s;
    __syncthreads();
    float t2 = 0.0f;
#pragma unroll
    for (int i = 0; i < 8; ++i) t2 += red[i];
    return t2;
}

// ===========================================================================
// K1: 217 blocks x 512 threads. All level-0 (inputs only). Proven structure.
// ===========================================================================
__global__ __launch_bounds__(512) void k_pre(
    const float* __restrict__ zW, const float* __restrict__ zb,
    const float* __restrict__ Wq, const float* __restrict__ bq,
    const float* __restrict__ Wk, const float* __restrict__ Wv,
    const float* __restrict__ Wo, const float* __restrict__ ce,
    const float* __restrict__ vW, const float* __restrict__ bo,
    float* __restrict__ ws)
{
    extern __shared__ float sm[];
    const int blk = blockIdx.x, t = threadIdx.x;
    const int lane = t & 63, w = t >> 6;

    if (blk < 128) {
        // ---------------- T1t / V1t ----------------
        const int f0 = blk * 4;
        float* ces = sm;            // 64*513
        float* wkv = sm + 32832;    // 8*512
        {
            const float4* ce4 = (const float4*)ce;
#pragma unroll 4
            for (int i = 0; i < 16; ++i) {
                const int idx4 = i * 512 + t;          // k*128 + c4
                const int k = idx4 >> 7, c4 = idx4 & 127;
                const float4 v = ce4[idx4];
                float* dst = &ces[k * 513 + c4 * 4];
                dst[0] = v.x; dst[1] = v.y; dst[2] = v.z; dst[3] = v.w;
            }
        }
        {
            const float4* Wk4 = (const float4*)Wk;
            const float4* Wv4 = (const float4*)Wv;
            float4* wkv4 = (float4*)wkv;
#pragma unroll
            for (int i = 0; i < 2; ++i) {
                const int idx = i * 512 + t;
                const int a = idx >> 7, c4 = idx & 127;
                wkv4[idx] = (a < 4) ? Wk4[(f0 + a) * 128 + c4]
                                    : Wv4[(f0 + a - 4) * 128 + c4];
            }
        }
        __syncthreads();
        float acc[8];
#pragma unroll
        for (int a = 0; a < 8; ++a) acc[a] = 0.0f;
        const int c0 = w * 64;
#pragma unroll 2
        for (int q4 = 0; q4 < 16; ++q4) {
            const int c = c0 + q4 * 4;
            const float cv0 = ces[lane * 513 + c + 0];
            const float cv1 = ces[lane * 513 + c + 1];
            const float cv2 = ces[lane * 513 + c + 2];
            const float cv3 = ces[lane * 513 + c + 3];
#pragma unroll
            for (int a = 0; a < 8; ++a) {
                const float4 wv4 = *(const float4*)&wkv[a * 512 + c];
                acc[a] = fmaf(wv4.x, cv0, acc[a]);
                acc[a] = fmaf(wv4.y, cv1, acc[a]);
                acc[a] = fmaf(wv4.z, cv2, acc[a]);
                acc[a] = fmaf(wv4.w, cv3, acc[a]);
            }
        }
        __syncthreads();
        float* part = sm;                              // reuse, 64*65
#pragma unroll
        for (int a = 0; a < 8; ++a) part[(a * 8 + w) * 65 + lane] = acc[a];
        __syncthreads();
        {
            float s = 0.0f;
#pragma unroll
            for (int ww = 0; ww < 8; ++ww) s += part[(w * 8 + ww) * 65 + lane];
            if (w < 4) ws[WS_T1 + (f0 + w) * 64 + lane] = s;
            else       ws[WS_V1 + (f0 + w - 4) * 64 + lane] = s;
        }

    } else if (blk < 192) {
        // ---------------- P1 ----------------
        const int f0 = (blk - 128) * 8;
        float* zl = sm;             // 512*64
        float* wq = sm + 32768;     // 8*512
        {
            const float4* zW4 = (const float4*)zW;
            float4* zl4 = (float4*)zl;
#pragma unroll 4
            for (int i = 0; i < 16; ++i) zl4[i * 512 + t] = zW4[i * 512 + t];
            const float4* Wq4 = (const float4*)Wq;
            float4* wq4 = (float4*)wq;
#pragma unroll
            for (int i = 0; i < 2; ++i)
                wq4[i * 512 + t] = Wq4[f0 * 128 + i * 512 + t];
        }
        __syncthreads();
        float acc[8];
#pragma unroll
        for (int a = 0; a < 8; ++a) acc[a] = 0.0f;
        const int e0 = w * 64;
#pragma unroll 2
        for (int q4 = 0; q4 < 16; ++q4) {
            const int e = e0 + q4 * 4;
            const float z0 = zl[(e + 0) * 64 + lane];
            const float z1 = zl[(e + 1) * 64 + lane];
            const float z2 = zl[(e + 2) * 64 + lane];
            const float z3 = zl[(e + 3) * 64 + lane];
#pragma unroll
            for (int fi = 0; fi < 8; ++fi) {
                const float4 q4v = *(const float4*)&wq[fi * 512 + e];
                acc[fi] = fmaf(q4v.x, z0, acc[fi]);
                acc[fi] = fmaf(q4v.y, z1, acc[fi]);
                acc[fi] = fmaf(q4v.z, z2, acc[fi]);
                acc[fi] = fmaf(q4v.w, z3, acc[fi]);
            }
        }
        __syncthreads();
        float* part = sm;
#pragma unroll
        for (int a = 0; a < 8; ++a) part[(a * 8 + w) * 65 + lane] = acc[a];
        __syncthreads();
        {
            float s = 0.0f;
#pragma unroll
            for (int ww = 0; ww < 8; ++ww) s += part[(w * 8 + ww) * 65 + lane];
            ws[WS_P1 + (f0 + w) * 64 + lane] = s;
        }

    } else if (blk < 200) {
        // ---------------- A = zW^T zW (+ colsum on first) ----------------
        const int r0 = (blk - 192) * 8;
        float* zl = sm;
        {
            const float4* zW4 = (const float4*)zW;
            float4* zl4 = (float4*)zl;
#pragma unroll 4
            for (int i = 0; i < 16; ++i) zl4[i * 512 + t] = zW4[i * 512 + t];
        }
        __syncthreads();
        float acc[8];
#pragma unroll
        for (int a = 0; a < 8; ++a) acc[a] = 0.0f;
        float cs = 0.0f;
        const int e0 = w * 64;
#pragma unroll 2
        for (int q4 = 0; q4 < 16; ++q4) {
            const int e = e0 + q4 * 4;
#pragma unroll
            for (int j = 0; j < 4; ++j) {
                const float zv = zl[(e + j) * 64 + lane];
                cs += zv;
                const float4 b0 = *(const float4*)&zl[(e + j) * 64 + r0];
                const float4 b1 = *(const float4*)&zl[(e + j) * 64 + r0 + 4];
                acc[0] = fmaf(b0.x, zv, acc[0]);
                acc[1] = fmaf(b0.y, zv, acc[1]);
                acc[2] = fmaf(b0.z, zv, acc[2]);
                acc[3] = fmaf(b0.w, zv, acc[3]);
                acc[4] = fmaf(b1.x, zv, acc[4]);
                acc[5] = fmaf(b1.y, zv, acc[5]);
                acc[6] = fmaf(b1.z, zv, acc[6]);
                acc[7] = fmaf(b1.w, zv, acc[7]);
            }
        }
        __syncthreads();
        float* part = sm;            // 64*65
        float* part2 = sm + 4160;    // 8*65
#pragma unroll
        for (int a = 0; a < 8; ++a) part[(a * 8 + w) * 65 + lane] = acc[a];
        if (blk == 192) part2[w * 65 + lane] = cs;
        __syncthreads();
        {
            float s = 0.0f;
#pragma unroll
            for (int ww = 0; ww < 8; ++ww) s += part[(w * 8 + ww) * 65 + lane];
            ws[WS_A + (r0 + w) * 64 + lane] = s;
        }
        if (blk == 192 && t < 64) {
            float s = 0.0f;
#pragma unroll
            for (int ww = 0; ww < 8; ++ww) s += part2[ww * 65 + t];
            ws[WS_COLSUM + t] = s;
        }

    } else if (blk < 208) {
        // ---------------- qzb ----------------
        const int f0 = (blk - 200) * 64;
        float zbr[8];
#pragma unroll
        for (int i = 0; i < 8; ++i) zbr[i] = zb[i * 64 + lane];
#pragma unroll
        for (int ff = 0; ff < 8; ++ff) {
            const int f = f0 + w * 8 + ff;
            float s = 0.0f;
#pragma unroll
            for (int i = 0; i < 8; ++i)
                s = fmaf(Wq[f * 512 + i * 64 + lane], zbr[i], s);
            s = wave_sum(s);
            if (lane == 0) ws[WS_QZB + f] = s + bq[f];
        }

    } else if (blk < 216) {
        // ---------------- wo0 = Wo^T vW ----------------
        const int e0 = (blk - 208) * 64;
        float s = 0.0f;
#pragma unroll 4
        for (int gi = 0; gi < 64; ++gi) {
            const int g = w * 64 + gi;
            s = fmaf(Wo[g * 512 + e0 + lane], vW[g], s);
        }
        float* part = sm;
        part[w * 65 + lane] = s;
        __syncthreads();
        if (t < 64) {
            float o = 0.0f;
#pragma unroll
            for (int ww = 0; ww < 8; ++ww) o += part[ww * 65 + t];
            ws[WS_WO0 + e0 + t] = o;
        }

    } else {
        // ---------------- misc: n2v, bo.vW ----------------
        float* red = sm;
        const float vwt = vW[t];
        const float n2v = block_sum512(vwt * vwt, red);
        if (t == 0) ws[WS_N2V] = n2v;
        const float bv_ = block_sum512(bo[t] * vwt, red);
        if (t == 0) ws[WS_BOVW] = bv_;
    }
}

// ===========================================================================
// K2: 11 blocks x 512 threads (level-1). No atomics, no fences. Proven (r10).
//  b0   : closed-form sigma (512-thread matvecs) + bv.wo0 + sigma_v
//  b1,b2: cvw0 = V1 @ wo0 ; ck0 = T1 @ qzb  (unscaled)
//  b3-10: GP_p over 64-f slices: GP[p][d][k] = sum_f T1t[f][k]*P1[f][d]
// ===========================================================================
__global__ __launch_bounds__(512) void k_mid(
    const float* __restrict__ bv, float* __restrict__ ws)
{
    extern __shared__ float sm[];
    const int blk = blockIdx.x, t = threadIdx.x;
    const int lane = t & 63, w = t >> 6;

    if (blk == 0) {
        float* As = sm;           // 64*65
        float* wL = sm + 4160;    // 64
        float* mvL = sm + 4224;   // 64
#pragma unroll
        for (int i = 0; i < 8; ++i) {
            const int idx = i * 512 + t;
            As[(idx >> 6) * 65 + (idx & 63)] = ws[WS_A + idx];
        }
        if (t < 64) wL[t] = ws[WS_COLSUM + t];
        __syncthreads();
        const int row = t >> 3, sub = t & 7;
#pragma unroll
        for (int it = 0; it < 4; ++it) {
            float p = 0.0f;
#pragma unroll
            for (int j = 0; j < 8; ++j)
                p = fmaf(As[row * 65 + sub * 8 + j], wL[sub * 8 + j], p);
            p += __shfl_xor(p, 1);
            p += __shfl_xor(p, 2);
            p += __shfl_xor(p, 4);
            __syncthreads();
            if (sub == 0) wL[row] = p;
            __syncthreads();
        }
        {
            float p = 0.0f;
#pragma unroll
            for (int j = 0; j < 8; ++j)
                p = fmaf(As[row * 65 + sub * 8 + j], wL[sub * 8 + j], p);
            p += __shfl_xor(p, 1);
            p += __shfl_xor(p, 2);
            p += __shfl_xor(p, 4);
            if (sub == 0) mvL[row] = p;
            __syncthreads();
        }
        if (w == 0) {
            const float w4 = wL[lane], mv = mvL[lane];
            const float s8 = wave_sum(w4 * w4);
            const float s9 = wave_sum(mv * w4);
            const float den = sqrtf(s8) + 1e-12f;
            const float n5sq = s9 / (den * den);
            const float n5 = sqrtf(n5sq);
            const float sig = n5sq / (n5 + 1e-12f);
            if (lane == 0) ws[WS_INV] = 1.0f / sig;
        } else if (w == 1) {
            float s = 0.0f;
#pragma unroll
            for (int i = 0; i < 8; ++i)
                s = fmaf(bv[i * 64 + lane], ws[WS_WO0 + i * 64 + lane], s);
            s = wave_sum(s);
            if (lane == 0) ws[WS_BVWO] = s;
        } else if (w == 2 && lane == 0) {
            const float n2 = ws[WS_N2V];
            const float rn = sqrtf(n2);
            float u = 1.0f / (1.0f + 1e-12f), s = 0.0f;
            for (int it = 0; it < 5; ++it) {
                const float nv = fabsf(u) * rn;
                const float vs = u / (nv + 1e-12f);
                s = n2 * vs;
                u = s / (fabsf(s) + 1e-12f);
            }
            ws[WS_INVSV] = 1.0f / (u * s);
        }

    } else if (blk < 3) {
        const int mat = (blk == 1) ? WS_V1 : WS_T1;
        const int vec = (blk == 1) ? WS_WO0 : WS_QZB;
        const int dst = (blk == 1) ? WS_CVW : WS_CK0;
        float s = 0.0f;
#pragma unroll 8
        for (int i = 0; i < 64; ++i) {
            const int e = w * 64 + i;
            s = fmaf(ws[mat + e * 64 + lane], ws[vec + e], s);
        }
        float* part = sm;
        part[w * 65 + lane] = s;
        __syncthreads();
        if (t < 64) {
            float o = 0.0f;
#pragma unroll
            for (int ww = 0; ww < 8; ++ww) o += part[ww * 65 + t];
            ws[dst + t] = o;
        }

    } else {
        // ---- GP_p over a 64-f slice ----
        const int p = blk - 3;
        const int f0 = p * 64;
        float* T1s = sm;           // 64*64
        float* P1s = sm + 4096;    // 64*64
        {
            const float4* a4 = (const float4*)&ws[WS_T1 + f0 * 64];
            const float4* b4 = (const float4*)&ws[WS_P1 + f0 * 64];
            float4* T14 = (float4*)T1s;
            float4* P14 = (float4*)P1s;
#pragma unroll
            for (int i = 0; i < 2; ++i) {
                T14[i * 512 + t] = a4[i * 512 + t];
                P14[i * 512 + t] = b4[i * 512 + t];
            }
        }
        __syncthreads();
        float acc[8];
#pragma unroll
        for (int j = 0; j < 8; ++j) acc[j] = 0.0f;
        const int d0 = w * 8;
#pragma unroll 2
        for (int f = 0; f < 64; ++f) {
            const float a = T1s[f * 64 + lane];
            const float4 p0 = *(const float4*)&P1s[f * 64 + d0];
            const float4 p1 = *(const float4*)&P1s[f * 64 + d0 + 4];
            acc[0] = fmaf(a, p0.x, acc[0]);
            acc[1] = fmaf(a, p0.y, acc[1]);
            acc[2] = fmaf(a, p0.z, acc[2]);
            acc[3] = fmaf(a, p0.w, acc[3]);
            acc[4] = fmaf(a, p1.x, acc[4]);
            acc[5] = fmaf(a, p1.y, acc[5]);
            acc[6] = fmaf(a, p1.z, acc[6]);
            acc[7] = fmaf(a, p1.w, acc[7]);
        }
#pragma unroll
        for (int j = 0; j < 8; ++j)
            ws[WS_GP + p * 4096 + (d0 + j) * 64 + lane] = acc[j];
    }
}

// ===========================================================================
// K3: k_sum. 72 blocks x 512 threads. Writes 8 XCD-local FIN replicas:
// block blk<64: r=blk&7 (its XCD under round-robin), c=blk>>3 -> GT chunk c
// into replica r. Blocks 64..71 (r=blk&7) write vectors/consts into replica r.
// Sum order ascending p, then *inv_s — bitwise identical to r10.
// ===========================================================================
__global__ __launch_bounds__(512) void k_sum(
    const float* __restrict__ geo, const float* __restrict__ vb,
    float* __restrict__ ws)
{
    const int blk = blockIdx.x, t = threadIdx.x;
    if (blk < 64) {
        const int r = blk & 7, c = blk >> 3;
        const float inv_s = ws[WS_INV];
        const int idx = c * 512 + t;
        float g = ws[WS_GP + idx];
#pragma unroll
        for (int p = 1; p < 8; ++p) g += ws[WS_GP + p * 4096 + idx];
        ws[FIN0 + r * FINSZ + idx] = g * inv_s;
    } else {
        const int r = blk & 7;
        const float inv_sv = ws[WS_INVSV];
        float* fin = ws + FIN0 + r * FINSZ;
        if (t < 64) {
            fin[FIN_CVW + t] = inv_sv * ws[WS_CVW + t];
            fin[FIN_CK0 + t] = ws[WS_CK0 + t];
        }
        if (t == 64) fin[FIN_CST] = inv_sv * (ws[WS_BVWO] + ws[WS_BOVW]) + vb[0];
        if (t == 65) fin[FIN_GS] = geo[0];
    }
}

// ===========================================================================
// K4: main. 256 blocks x 256 threads; 16 rows/block, 4 rows/wave, lane = k.
// Stages from FIN replica (blockIdx&7) — XCD-local under round-robin dispatch
// (pure perf heuristic; correct regardless of placement).
// Yt recomputed in-kernel from clean cc input (proven r8-r10).
// ===========================================================================
__global__ __launch_bounds__(256) void k_main(
    const float* __restrict__ z, const float* __restrict__ rw,
    const float* __restrict__ cc, const float* __restrict__ ws,
    float* __restrict__ out)
{
    __shared__ float sGt[4096];
    __shared__ float sYt[4160];   // [64][65] padded
    __shared__ float sCvw[64], sCk0[64], sNy2[64], sSc[2];
    const int t = threadIdx.x;
    const int lane = t & 63, wid = t >> 6;
    const float* fin = ws + FIN0 + (blockIdx.x & 7) * FINSZ;

    // ---- stage FIN (contiguous, XCD-local) ----
    {
        const float4* fin4 = (const float4*)fin;
        float4* sGt4 = (float4*)sGt;
#pragma unroll
        for (int i = 0; i < 4; ++i) sGt4[i * 256 + t] = fin4[i * 256 + t];
    }
    if (t < 64) {
        sCvw[t] = fin[FIN_CVW + t];
        sCk0[t] = fin[FIN_CK0 + t];
    }
    if (t == 0) {
        sSc[0] = fin[FIN_CST];
        sSc[1] = fin[FIN_GS];
    }
    // ---- recompute chart-center projection from cc (thread = (k, quarter)) ----
    {
        const int k = t >> 2, q = t & 3;
        const float4* cc4 = (const float4*)cc;
        float4 v[4];
        float n2 = 0.0f;
#pragma unroll
        for (int j = 0; j < 4; ++j) {
            v[j] = cc4[k * 16 + q * 4 + j];
            n2 = fmaf(v[j].x, v[j].x, n2);
            n2 = fmaf(v[j].y, v[j].y, n2);
            n2 = fmaf(v[j].z, v[j].z, n2);
            n2 = fmaf(v[j].w, v[j].w, n2);
        }
        n2 += __shfl_xor(n2, 1);
        n2 += __shfl_xor(n2, 2);
        const float n = sqrtf(n2);
        const float scale = fminf(1.0f, (1.0f - 1e-5f) / fmaxf(n, 1e-12f));
        float s2 = 0.0f;
#pragma unroll
        for (int j = 0; j < 4; ++j) {
            const float y0 = v[j].x * scale, y1 = v[j].y * scale;
            const float y2 = v[j].z * scale, y3 = v[j].w * scale;
            const int dd = q * 16 + j * 4;
            sYt[(dd + 0) * 65 + k] = y0;
            sYt[(dd + 1) * 65 + k] = y1;
            sYt[(dd + 2) * 65 + k] = y2;
            sYt[(dd + 3) * 65 + k] = y3;
            s2 = fmaf(y0, y0, s2); s2 = fmaf(y1, y1, s2);
            s2 = fmaf(y2, y2, s2); s2 = fmaf(y3, y3, s2);
        }
        s2 += __shfl_xor(s2, 1);
        s2 += __shfl_xor(s2, 2);
        if (q == 0) sNy2[k] = s2;
    }
    __syncthreads();

    const float gs = sSc[1], cst = sSc[0];
    const float rs512 = 0.04419417382415922f;   // 1/sqrt(512)
#pragma unroll
    for (int rr = 0; rr < 4; ++rr) {
        const int b = blockIdx.x * 16 + wid * 4 + rr;
        const float zl = z[b * 64 + lane];
        const float rwk = rw[b * 64 + lane];
        float dot = 0.0f, diff2 = 0.0f, nz2 = 0.0f;
#pragma unroll 8
        for (int dd = 0; dd < 64; ++dd) {
            const float zd = __shfl(zl, dd);
            nz2 = fmaf(zd, zd, nz2);
            dot = fmaf(zd, sGt[dd * 64 + lane], dot);
            const float df = zd - sYt[dd * 65 + lane];
            diff2 = fmaf(df, df, diff2);
        }
        const float den = (1.0f - nz2) * (1.0f - sNy2[lane]);
        float arg = 1.0f + 2.0f * diff2 / fmaxf(den, 1e-12f);
        arg = fmaxf(arg, 1.0f + 1e-7f);
        const float dg = acoshf(arg);
        const float score = rwk * (dot + sCk0[lane]) * rs512 - gs * dg * dg;
        float mx = score;
#pragma unroll
        for (int o = 32; o; o >>= 1) mx = fmaxf(mx, __shfl_xor(mx, o));
        const float e = expf(score - mx);
        float s1 = e, s2 = e * rwk * sCvw[lane];
#pragma unroll
        for (int o = 32; o; o >>= 1) { s1 += __shfl_xor(s1, o); s2 += __shfl_xor(s2, o); }
        if (lane == 0) out[b] = s2 / s1 + cst;
    }
}

extern "C" void kernel_launch(void* const* d_in, const int* in_sizes, int n_in,
                              void* d_out, int out_size, void* d_ws, size_t ws_size,
                              hipStream_t stream)
{
    (void)in_sizes; (void)n_in; (void)out_size; (void)ws_size;
    const float* z   = (const float*)d_in[0];
    const float* rw  = (const float*)d_in[1];
    const float* cem = (const float*)d_in[2];
    const float* cc  = (const float*)d_in[3];
    const float* zW  = (const float*)d_in[4];
    const float* zb  = (const float*)d_in[5];
    const float* Wq  = (const float*)d_in[6];
    const float* bq  = (const float*)d_in[7];
    const float* Wk  = (const float*)d_in[8];
    // d_in[9] = bk: softmax-shift-invariant, provably unused
    const float* Wv  = (const float*)d_in[10];
    const float* bv  = (const float*)d_in[11];
    const float* Wo  = (const float*)d_in[12];
    const float* bo  = (const float*)d_in[13];
    const float* geo = (const float*)d_in[14];
    const float* vW  = (const float*)d_in[15];
    const float* vb  = (const float*)d_in[16];
    float* ws  = (float*)d_ws;
    float* out = (float*)d_out;

    hipLaunchKernelGGL(k_pre,  dim3(217), dim3(512), PRE_LDSB, stream,
                       zW, zb, Wq, bq, Wk, Wv, Wo, cem, vW, bo, ws);
    hipLaunchKernelGGL(k_mid,  dim3(11),  dim3(512), MID_LDSB, stream, bv, ws);
    hipLaunchKernelGGL(k_sum,  dim3(72),  dim3(512), 0, stream, geo, vb, ws);
    hipLaunchKernelGGL(k_main, dim3(256), dim3(256), 0, stream,
                       z, rw, cc, ws, out);
}